// Round 15
// baseline (69.751 us; speedup 1.0000x reference)
//
#include <hip/hip_runtime.h>

// MorphologicalLayer: ops='co', windows=[51,25] on [16, 8, 262144] f32.
//   y1 = max51(zp(x)); y2 = min51(zp(y1)); y3 = min25(zp(y2)); y4 = max25(zp(y3))
// E=64 elems/lane, one wave per block (4096 locals/chunk, NSLOT=1048 f4 =
// 16768 B LDS). Per stage, windows are split at sub-block boundaries; the
// near-boundary prefixes come from OWN REGISTERS (r[32..63] etc), so LDS halo
// per element halves vs E=32 (38 f4 per 64 elems) and prefix VALU amortizes.
// Zero __syncthreads (wave-private LDS, per-wave DS FIFO + fences).
// Validity (interior): st1 valid locals [0,4096); st2(K75) <=4021 (prefix-
// aware: lane62/63 garbage only where prefix touches stale slots >=4096);
// st3(K25) <=3997. Edge chain (51,51,25,25): <=4045/4021/3997.
// Claimed locals [2, 3998) -> T_W = 3996.

#define L_ROW   262144
#define N_ROWS  128
#define BLOCK   64           // one wave
#define E       64           // elements per lane
#define T_W     3996         // claimed outputs per chunk (mult of 4)
#define N_CHUNKS 66          // ceil(262144 / 3996)
#define NSLOT   1048         // f4 slots (4192 floats, 16768 B)

typedef float f32x2 __attribute__((ext_vector_type(2)));

// XOR swizzle at float4 granularity: flips slot bits 0-2 by bits 4-6.
// Involution; bijective on mult-of-8 ranges; spreads the per-lane stride-16
// slot patterns (own base 16L, halo base 16L+16) across all 8 bank-quads.
__device__ __forceinline__ int swz(int s) { return s ^ ((s >> 4) & 7); }

#define WFENCE() asm volatile("" ::: "memory")

template<bool MX>
__device__ __forceinline__ float mm(float a, float b) {
  return MX ? fmaxf(a, b) : fminf(a, b);
}

// in-place suffix-scan over 32 floats (blocked-8 + cascade): r[i]=mm(r[i..31])
template<bool MX>
__device__ __forceinline__ void suffix32(float* r) {
#pragma unroll
  for (int b = 0; b < 4; ++b)
#pragma unroll
    for (int i = 8*b + 6; i >= 8*b; --i) r[i] = mm<MX>(r[i], r[i+1]);
  const float S2 = r[24];
  const float S1 = mm<MX>(r[16], S2);
  const float S0 = mm<MX>(r[8],  S1);
#pragma unroll
  for (int i = 0;  i < 8;  ++i) r[i] = mm<MX>(r[i], S0);
#pragma unroll
  for (int i = 8;  i < 16; ++i) r[i] = mm<MX>(r[i], S1);
#pragma unroll
  for (int i = 16; i < 24; ++i) r[i] = mm<MX>(r[i], S2);
}

// in-place suffix-scan over 16 floats
template<bool MX>
__device__ __forceinline__ void suffix16(float* r) {
#pragma unroll
  for (int i = 6; i >= 0; --i)  r[i] = mm<MX>(r[i], r[i+1]);
#pragma unroll
  for (int i = 14; i >= 8; --i) r[i] = mm<MX>(r[i], r[i+1]);
  const float S = r[8];
#pragma unroll
  for (int i = 0; i < 8; ++i) r[i] = mm<MX>(r[i], S);
}

template<int NF4>
__device__ __forceinline__ void read_h(const float4* buf, int base, float* h) {
#pragma unroll
  for (int j = 0; j < NF4; ++j) {
    float4 v = buf[swz(base + j)];
    h[4*j] = v.x; h[4*j+1] = v.y; h[4*j+2] = v.z; h[4*j+3] = v.w;
  }
}

template<int N, bool MX>   // in-block prefixes (blocks of 8), N mult of 8
__device__ __forceinline__ void prefix_blocks(float* h) {
#pragma unroll
  for (int b = 0; b < N/8; ++b)
#pragma unroll
    for (int i = 8*b + 1; i < 8*b + 8; ++i) h[i] = mm<MX>(h[i-1], h[i]);
}

template<int N, bool MX>   // sequential cascade after prefix_blocks
__device__ __forceinline__ void cascade(float* h) {
#pragma unroll
  for (int b = 1; b < N/8; ++b) {
    const float cc = h[8*b - 1];
#pragma unroll
    for (int i = 8*b; i < 8*b + 8; ++i) h[i] = mm<MX>(cc, h[i]);
  }
}

template<int N, bool MX>   // cascade seeded with external carry
__device__ __forceinline__ void cascade_from(float* h, float carry) {
  float cc = carry;
#pragma unroll
  for (int b = 0; b < N/8; ++b) {
#pragma unroll
    for (int i = 8*b; i < 8*b + 8; ++i) h[i] = mm<MX>(cc, h[i]);
    cc = h[8*b + 7];
  }
}

__device__ __forceinline__ void edge_zero64(float* r, int goff, int lane, bool edge) {
  if (edge) {
    const int base = goff + lane * E;
#pragma unroll
    for (int i = 0; i < E; ++i)
      if ((unsigned)(base + i) >= (unsigned)L_ROW) r[i] = 0.0f;
  }
}

__device__ __forceinline__ void writeback(const float* r, float4* buf, int b16) {
  WFENCE();
#pragma unroll
  for (int j = 0; j < 16; ++j)
    buf[swz(b16 + j)] = make_float4(r[4*j], r[4*j+1], r[4*j+2], r[4*j+3]);
  WFENCE();
}

// K=51: sub-A (i 0..31, boundary 32): i<=13 prefix within r[32..63] (tp);
// i>=14 = mm(RA, PH[i-14]).  sub-B (i 32..63, boundary 64): PH[i-14].
// PH = prefix over H (rel local 64+j).
template<bool MX>
__device__ __forceinline__ void stage51(float* r, float4* buf, int lane,
                                        int goff, bool edge) {
  const int hb = lane * 16 + 16;
  // tp[i] = mm(r[32..50+i]) i=0..13; RA = mm(r[32..63])
  float tp[14];
  float c = r[32];
#pragma unroll
  for (int j = 1; j < 32; ++j) {
    c = mm<MX>(c, r[32 + j]);
    if (j >= 18) tp[j - 18] = c;
  }
  const float RA = c;
  // phase 1: H[0..19] (rel 64..83)
  float h[20];
  read_h<5>(buf, hb, h);
  prefix_blocks<16, MX>(h);
#pragma unroll
  for (int i = 17; i < 20; ++i) h[i] = mm<MX>(h[i-1], h[i]);
  { const float cc = h[7];
#pragma unroll
    for (int i = 8; i < 16; ++i) h[i] = mm<MX>(cc, h[i]); }
  { const float cc = h[15];
#pragma unroll
    for (int i = 16; i < 20; ++i) h[i] = mm<MX>(cc, h[i]); }
  const float s18 = h[18], s19 = h[19];

  suffix32<MX>(r);
#pragma unroll
  for (int i = 0; i < 14; ++i)  r[i] = mm<MX>(r[i], tp[i]);
#pragma unroll
  for (int i = 14; i < 32; ++i) r[i] = mm<MX>(r[i], mm<MX>(RA, h[i-14]));

  // phase 2: H[20..51] (rel 84..115), prefixes PH[20..49] with carry s19
  float h2[32];
  read_h<8>(buf, hb + 5, h2);
  prefix_blocks<32, MX>(h2);
  cascade_from<32, MX>(h2, s19);

  suffix32<MX>(r + 32);
  r[32] = mm<MX>(r[32], s18);
  r[33] = mm<MX>(r[33], s19);
#pragma unroll
  for (int i = 34; i < 64; ++i) r[i] = mm<MX>(r[i], h2[i-34]);

  edge_zero64(r, goff, lane, edge);
  writeback(r, buf, lane * 16);
}

// K=75: sub-A: out[i] = mm(SA[i], RA, PH[i+10]); sub-B: mm(SB[i], PH[i+10]).
template<bool MX>
__device__ __forceinline__ void stage75(float* r, float4* buf, int lane,
                                        int goff, bool edge) {
  const int hb = lane * 16 + 16;
  float c = r[32];
#pragma unroll
  for (int j = 1; j < 32; ++j) c = mm<MX>(c, r[32 + j]);
  const float RA = c;
  // phase 1: H[0..43] (rel 64..107) -> PH[0..43]
  float h[44];
  read_h<11>(buf, hb, h);
  prefix_blocks<40, MX>(h);
#pragma unroll
  for (int i = 41; i < 44; ++i) h[i] = mm<MX>(h[i-1], h[i]);
  cascade<40, MX>(h);
  { const float cc = h[39];
#pragma unroll
    for (int i = 40; i < 44; ++i) h[i] = mm<MX>(cc, h[i]); }
  const float c42 = h[42], c43 = h[43];

  suffix32<MX>(r);
#pragma unroll
  for (int i = 0; i < 32; ++i) r[i] = mm<MX>(r[i], mm<MX>(RA, h[i+10]));

  // phase 2: H[44..75] (rel 108..139) -> PH[44..73] with carry c43
  float h2[32];
  read_h<8>(buf, hb + 11, h2);
  prefix_blocks<32, MX>(h2);
  cascade_from<32, MX>(h2, c43);

  suffix32<MX>(r + 32);
  r[32] = mm<MX>(r[32], c42);
  r[33] = mm<MX>(r[33], c43);
#pragma unroll
  for (int i = 34; i < 64; ++i) r[i] = mm<MX>(r[i], h2[i-34]);

  edge_zero64(r, goff, lane, edge);
  writeback(r, buf, lane * 16);
}

// K=25: 4 sub-chunks of 16 (boundaries 16/32/48/64). p0/p1 from own regs;
// p2 bridges r[48..63]+H[0..7]; sub-3 uses PH over H[0..23].
template<bool MX>
__device__ __forceinline__ void stage25(float* r, float4* buf, int lane,
                                        int goff, bool edge) {
  const int hb = lane * 16 + 16;
  float h[24];                              // rel 64..87 (raw)
  read_h<6>(buf, hb, h);

  // p2[k] = mm(rel [48, 56+k]) k=0..15  (raw r[48..63] + raw h[0..7])
  float p2[16];
  { float c = r[48];
#pragma unroll
    for (int j = 1; j < 16; ++j) { c = mm<MX>(c, r[48+j]); if (j >= 8) p2[j-8] = c; }
#pragma unroll
    for (int j = 0; j < 8; ++j)  { c = mm<MX>(c, h[j]); p2[8+j] = c; } }
  // p1[k] = mm(rel [32, 40+k]) k=0..15  (raw r[32..55])
  float p1[16];
  { float c = r[32];
#pragma unroll
    for (int j = 1; j < 24; ++j) { c = mm<MX>(c, r[32+j]); if (j >= 8) p1[j-8] = c; } }
  // PH over h[0..23] (in place; raw h consumed by p2 above)
  prefix_blocks<24, MX>(h);
  cascade<24, MX>(h);

  suffix16<MX>(r + 48);
#pragma unroll
  for (int i = 48; i < 64; ++i) r[i] = mm<MX>(r[i], h[i-40]);

  // p0[k] = mm(rel [16, 24+k]) k=0..15  (raw r[16..39])
  float p0[16];
  { float c = r[16];
#pragma unroll
    for (int j = 1; j < 24; ++j) { c = mm<MX>(c, r[16+j]); if (j >= 8) p0[j-8] = c; } }

  suffix16<MX>(r + 32);
#pragma unroll
  for (int i = 32; i < 48; ++i) r[i] = mm<MX>(r[i], p2[i-32]);
  suffix16<MX>(r + 16);
#pragma unroll
  for (int i = 16; i < 32; ++i) r[i] = mm<MX>(r[i], p1[i-16]);
  suffix16<MX>(r);
#pragma unroll
  for (int i = 0; i < 16; ++i)  r[i] = mm<MX>(r[i], p0[i]);

  edge_zero64(r, goff, lane, edge);
  writeback(r, buf, lane * 16);
}

__global__ __launch_bounds__(BLOCK)
void morph_co_kernel(const float* __restrict__ x, float* __restrict__ out) {
  __shared__ float4 buf[NSLOT];             // 16768 B

  const int lane = threadIdx.x;
  const int c    = blockIdx.x;              // chunk 0..65
  const int row  = blockIdx.y;

  const float* __restrict__ xrow = x   + (size_t)row * L_ROW;
  float* __restrict__       orow = out + (size_t)row * L_ROW;

  const int ob = c * T_W;                   // claimed outputs [ob, ob+T_W)
  const int c0 = ob - 76;                   // buffer float 0 = x[c0]; 4-aligned
  const bool edge = (c == 0) || (c == N_CHUNKS - 1);

  // ---- staging: buf[s] = x[c0 + 4*swz(s)] (swizzled layout)
  if (!edge) {
#pragma unroll
    for (int it = 0; it < 16; ++it) {
      const int s = it * 64 + lane;
      const float* g = xrow + c0 + 4 * swz(s);
      __builtin_amdgcn_global_load_lds(
          (const __attribute__((address_space(1))) void*)g,
          (__attribute__((address_space(3))) void*)(&buf[it * 64]), 16, 0, 0);
    }
    if (lane < NSLOT - 1024) {              // tail 24 slots
      const int s = 1024 + lane;
      const float* g = xrow + c0 + 4 * swz(s);
      __builtin_amdgcn_global_load_lds(
          (const __attribute__((address_space(1))) void*)g,
          (__attribute__((address_space(3))) void*)(&buf[1024]), 16, 0, 0);
    }
    asm volatile("s_waitcnt vmcnt(0)" ::: "memory");
  } else {
#pragma unroll
    for (int it = 0; it < 17; ++it) {
      const int s = it * 64 + lane;
      if (s < NSLOT) {
        const int g = c0 + 4 * s;
        float4 v;
        v.x = ((unsigned)(g + 0) < (unsigned)L_ROW) ? xrow[g + 0] : 0.0f;
        v.y = ((unsigned)(g + 1) < (unsigned)L_ROW) ? xrow[g + 1] : 0.0f;
        v.z = ((unsigned)(g + 2) < (unsigned)L_ROW) ? xrow[g + 2] : 0.0f;
        v.w = ((unsigned)(g + 3) < (unsigned)L_ROW) ? xrow[g + 3] : 0.0f;
        buf[swz(s)] = v;
      }
    }
    WFENCE();
  }

  // ---- own block -> registers
  float r[E];
  {
    const int b16 = lane * 16;
#pragma unroll
    for (int j = 0; j < 16; ++j) {
      float4 v = buf[swz(b16 + j)];
      r[4*j] = v.x; r[4*j+1] = v.y; r[4*j+2] = v.z; r[4*j+3] = v.w;
    }
  }

  if (!edge) {
    // interior: max51 -> min75 (= min25∘min51) -> max25
    stage51<true >(r, buf, lane, 0, false);
    stage75<false>(r, buf, lane, 0, false);
    stage25<true >(r, buf, lane, 0, false);
  } else {
    // exact chain with per-stage zero padding (offsets 25/50/62/74)
    stage51<true >(r, buf, lane, c0 + 25, true);
    stage51<false>(r, buf, lane, c0 + 50, true);
    stage25<false>(r, buf, lane, c0 + 62, true);
    stage25<true >(r, buf, lane, c0 + 74, true);
  }

  // ---- copy-out: buffer float l holds out[ob + l - 2], claimed l in
  // [2, T_W+2). Lane-contiguous LDS reads; 8B-aligned f32x2 global stores.
  if (!edge) {
#pragma unroll
    for (int it = 0; it < 16; ++it) {
      const int u = it * 64 + lane;
      if (u <= T_W / 4) {                   // 999
        float4 v = buf[swz(u)];
        float* p = orow + ob + 4 * u;
        if (u >= 1)       *reinterpret_cast<f32x2*>(p - 2) = f32x2{v.x, v.y};
        if (u < T_W / 4)  *reinterpret_cast<f32x2*>(p)     = f32x2{v.z, v.w};
      }
    }
  } else {
    const int hi = min(ob + T_W, L_ROW);
#pragma unroll
    for (int it = 0; it < 16; ++it) {
      const int u = it * 64 + lane;
      if (u <= T_W / 4) {
        float4 v = buf[swz(u)];
        const int p = ob - 2 + 4 * u;
        if (p     >= ob && p     < hi) orow[p]     = v.x;
        if (p + 1 >= ob && p + 1 < hi) orow[p + 1] = v.y;
        if (p + 2 >= ob && p + 2 < hi) orow[p + 2] = v.z;
        if (p + 3 >= ob && p + 3 < hi) orow[p + 3] = v.w;
      }
    }
  }
}

extern "C" void kernel_launch(void* const* d_in, const int* in_sizes, int n_in,
                              void* d_out, int out_size, void* d_ws, size_t ws_size,
                              hipStream_t stream) {
  const float* x = (const float*)d_in[0];
  float* out = (float*)d_out;
  dim3 grid(N_CHUNKS, N_ROWS);              // 66 x 128 one-wave blocks
  morph_co_kernel<<<grid, BLOCK, 0, stream>>>(x, out);
}

// Round 16
// 49.474 us; speedup vs baseline: 1.4098x; 1.4098x over previous
//
#include <hip/hip_runtime.h>

// MorphologicalLayer: ops='co', windows=[51,25] on [16, 8, 262144] f32.
//   y1 = max51(zp(x)); y2 = min51(zp(y1)); y3 = min25(zp(y2)); y4 = max25(zp(y3))
// R10 champion structure: wave-independent chunks (4 waves/block, private
// 8448 B LDS regions, ZERO __syncthreads) + one change: copy-out uses
// 16B-aligned FULL-WIDTH float4 NON-TEMPORAL stores (LDS dual-slot repack).
// NT keeps the 131 MB output stream from evicting the L3-resident input
// (FETCH was 68 MB of a 128 MB input); full-line coverage avoids R6's
// partial-line NT amplification.
// Interior chunks fuse min51∘min25 = min75 (3 stages); first/last chunk of
// each row run the exact 4-stage chain with per-stage zero clamps.
// Validity chain (interior): stage1(K51, bh<=507: no clamp) valid [0,2048);
// stage2(K75, bh<=501) valid [0,1974); stage3(K25) valid [0,1950);
// claimed locals [2,1946) -> T_W=1944. Edge chain also covered.

#define L_ROW   262144
#define N_ROWS  128          // B*C = 16*8
#define BLOCK   256          // 4 independent waves
#define E       32           // elements per lane
#define EF4     8            // E/4
#define T_W     1944         // claimed outputs per wave chunk (mult of 4)
#define N_CHUNKS 135         // ceil(262144 / 1944)
#define NSLOT   528          // f4 slots per wave region (2112 floats, 8448 B)

typedef float f32x2 __attribute__((ext_vector_type(2)));
typedef float f32x4 __attribute__((ext_vector_type(4)));

// XOR swizzle at float4 granularity: spreads per-lane 128B-strided accesses
// across all 8 bank-quads. Involution, bijective on mult-of-8 ranges.
__device__ __forceinline__ int swz(int s) { return s ^ ((s >> 3) & 7); }

// Compiler-only memory fence: DS ops from one wave execute in program order
// in HW; this stops the compiler reordering them (per-thread index ranges are
// disjoint, so it otherwise legally could).
#define WFENCE() asm volatile("" ::: "memory")

template<bool MX>
__device__ __forceinline__ float mm(float a, float b) {
  return MX ? fmaxf(a, b) : fminf(a, b);
}

__device__ __forceinline__ void edge_zero(float* r, int goff, int lane, bool edge) {
  if (edge) {
    const int base = goff + lane * E;
#pragma unroll
    for (int i = 0; i < E; ++i)
      if ((unsigned)(base + i) >= (unsigned)L_ROW) r[i] = 0.0f;
  }
}

__device__ __forceinline__ void writeback(const float* r, float4* buf, int b4) {
  WFENCE();   // this stage's halo reads stay above the stores
#pragma unroll
  for (int j = 0; j < EF4; ++j)
    buf[swz(b4 + j)] = make_float4(r[4*j], r[4*j+1], r[4*j+2], r[4*j+3]);
  WFENCE();   // next stage's reads stay below the stores
}

// K in {51, 75}: all windows [i, i+K-1], i in [0,32), straddle the boundary
// at 32. out[i] = mm(S[i], Base&Top prefix at i+K-1). Writes back for
// neighbors. Lanes whose halo reads would exceed the region are clamped
// (K-DEPENDENT bound: max slot read is bh+15+BN); their outputs are garbage
// but lie beyond the claimed range (validity chain in header).
template<int K, bool MX>
__device__ __forceinline__ void stage_big(float* r, float4* buf, int lane,
                                          int goff, bool edge) {
  constexpr int BLEN = K - 33;              // 18 / 42 (== 2 mod 4)
  constexpr int BN   = (BLEN + 2) / 4;      // 5 / 11 base-side f4 slots
  const int b4 = lane * EF4;
  const int bh = min(b4, NSLOT - 16 - BN);  // K=51: 507 (no lane clamped);
                                            // K=75: 501 (lane 63 clamped)

  // Base = mm over halo floats [32 .. K-2], lane-wise accumulators
  float4 v0 = buf[swz(bh + 8)];
  float a0 = v0.x, a1 = v0.y, a2 = v0.z, a3 = v0.w;
#pragma unroll
  for (int j = 1; j < BN - 1; ++j) {
    float4 v = buf[swz(bh + 8 + j)];
    a0 = mm<MX>(a0, v.x); a1 = mm<MX>(a1, v.y);
    a2 = mm<MX>(a2, v.z); a3 = mm<MX>(a3, v.w);
  }
  float4 vl = buf[swz(bh + 8 + BN - 1)];    // 2 base floats + T[0], T[1]
  const float Base = mm<MX>(mm<MX>(mm<MX>(a0, a1), mm<MX>(a2, a3)),
                            mm<MX>(vl.x, vl.y));
  // Top: halo floats [K-1 .. K+30]
  float T[34];
  T[0] = vl.z; T[1] = vl.w;
#pragma unroll
  for (int j = 0; j < 8; ++j) {
    float4 v = buf[swz(bh + 8 + BN + j)];
    T[2+4*j] = v.x; T[3+4*j] = v.y; T[4+4*j] = v.z; T[5+4*j] = v.w;
  }

  // S[i] = mm(r[i..31]) via blocked-8 suffix + cascade (in place)
#pragma unroll
  for (int b = 0; b < 4; ++b)
#pragma unroll
    for (int i = 8*b + 6; i >= 8*b; --i) r[i] = mm<MX>(r[i], r[i+1]);
  const float S2 = r[24];
  const float S1 = mm<MX>(r[16], S2);
  const float S0 = mm<MX>(r[8],  S1);
#pragma unroll
  for (int i = 0;  i < 8;  ++i) r[i] = mm<MX>(r[i], S0);
#pragma unroll
  for (int i = 8;  i < 16; ++i) r[i] = mm<MX>(r[i], S1);
#pragma unroll
  for (int i = 16; i < 24; ++i) r[i] = mm<MX>(r[i], S2);

  // Top prefix within blocks of 8 + head cascade
#pragma unroll
  for (int b = 0; b < 4; ++b)
#pragma unroll
    for (int i = 8*b + 1; i < 8*b + 8; ++i) T[i] = mm<MX>(T[i-1], T[i]);
  const float G0 = mm<MX>(Base, T[7]);
  const float G1 = mm<MX>(G0,   T[15]);
  const float G2 = mm<MX>(G1,   T[23]);

  // out[i] = mm(S[i], head, T[i])
#pragma unroll
  for (int i = 0;  i < 8;  ++i) r[i] = mm<MX>(r[i], mm<MX>(Base, T[i]));
#pragma unroll
  for (int i = 8;  i < 16; ++i) r[i] = mm<MX>(r[i], mm<MX>(G0, T[i]));
#pragma unroll
  for (int i = 16; i < 24; ++i) r[i] = mm<MX>(r[i], mm<MX>(G1, T[i]));
#pragma unroll
  for (int i = 24; i < 32; ++i) r[i] = mm<MX>(r[i], mm<MX>(G2, T[i]));

  edge_zero(r, goff, lane, edge);
  writeback(r, buf, b4);
}

// K = 25: chunk A (i in [0,16)) straddles 16; chunk B (i in [16,32)) straddles 32.
template<bool MX>
__device__ __forceinline__ void stage_25(float* r, float4* buf, int lane,
                                         int goff, bool edge) {
  const int b4 = lane * EF4;
  float h[24];                              // halo floats [32..55]
#pragma unroll
  for (int j = 0; j < 6; ++j) {
    float4 v = buf[swz(b4 + 8 + j)];        // max slot 504+13 = 517 < 528
    h[4*j] = v.x; h[4*j+1] = v.y; h[4*j+2] = v.z; h[4*j+3] = v.w;
  }

  // t = prefix over raw r[24..31] (before in-place S destroys it)
  float t[8];
  t[0] = r[24];
#pragma unroll
  for (int i = 1; i < 8; ++i) t[i] = mm<MX>(t[i-1], r[24+i]);
  // S_B over r[16..31] (blocked)
#pragma unroll
  for (int i = 30; i >= 24; --i) r[i] = mm<MX>(r[i], r[i+1]);
#pragma unroll
  for (int i = 22; i >= 16; --i) r[i] = mm<MX>(r[i], r[i+1]);
  const float cA = r[16];                   // mm(raw r[16..23])
  const float A3 = r[24];
#pragma unroll
  for (int i = 16; i < 24; ++i) r[i] = mm<MX>(r[i], A3);
  // S_A over r[0..15]
#pragma unroll
  for (int i = 14; i >= 8; --i) r[i] = mm<MX>(r[i], r[i+1]);
#pragma unroll
  for (int i = 6;  i >= 0; --i) r[i] = mm<MX>(r[i], r[i+1]);
  const float A1 = r[8];
#pragma unroll
  for (int i = 0; i < 8; ++i) r[i] = mm<MX>(r[i], A1);
  // halo prefix in blocks of 8
#pragma unroll
  for (int b = 0; b < 3; ++b)
#pragma unroll
    for (int i = 8*b + 1; i < 8*b + 8; ++i) h[i] = mm<MX>(h[i-1], h[i]);
  const float aB  = h[7];                   // mm(halo 32..39)
  const float cA2 = mm<MX>(cA, t[7]);       // mm(own 16..31)
  const float G1  = mm<MX>(aB, h[15]);      // mm(halo 32..47)
  // out[i] = mm(S, head, scan)   windows [i, i+24]
#pragma unroll
  for (int i = 0;  i < 8;  ++i) r[i] = mm<MX>(r[i], mm<MX>(cA,  t[i]));
#pragma unroll
  for (int i = 8;  i < 16; ++i) r[i] = mm<MX>(r[i], mm<MX>(cA2, h[i-8]));
#pragma unroll
  for (int i = 16; i < 24; ++i) r[i] = mm<MX>(r[i], mm<MX>(aB,  h[i-8]));
#pragma unroll
  for (int i = 24; i < 32; ++i) r[i] = mm<MX>(r[i], mm<MX>(G1,  h[i-8]));

  edge_zero(r, goff, lane, edge);
  writeback(r, buf, b4);
}

__global__ __launch_bounds__(BLOCK)
void morph_co_kernel(const float* __restrict__ x, float* __restrict__ out) {
  __shared__ float4 lds4[4 * NSLOT];        // 33792 B

  const int w    = threadIdx.x >> 6;
  const int lane = threadIdx.x & 63;
  const int c    = blockIdx.x * 4 + w;      // chunk index within the row
  const int row  = blockIdx.y;
  if (c >= N_CHUNKS) return;                // no barriers in kernel: legal

  float4* buf = lds4 + w * NSLOT;           // private per-wave region
  const float* __restrict__ xrow = x   + (size_t)row * L_ROW;
  float* __restrict__       orow = out + (size_t)row * L_ROW;

  const int ob = c * T_W;                   // claimed outputs [ob, ob+T_W)
  const int c0 = ob - 76;                   // buffer float 0 = x[c0]; 4-aligned
  const bool edge = (c == 0) || (c == N_CHUNKS - 1);
  const int b4 = lane * EF4;

  // ---- staging: global -> private LDS region (swizzled layout)
  if (!edge) {
#pragma unroll
    for (int it = 0; it < 9; ++it) {
      const int s = it * 64 + lane;
      if (s < NSLOT) {
        const float* g = xrow + c0 + 4 * swz(s);   // pre-swizzled source
        __builtin_amdgcn_global_load_lds(
            (const __attribute__((address_space(1))) void*)g,
            (__attribute__((address_space(3))) void*)(&buf[it * 64]), 16, 0, 0);
      }
    }
    asm volatile("s_waitcnt vmcnt(0)" ::: "memory");
  } else {
#pragma unroll
    for (int it = 0; it < 9; ++it) {
      const int s = it * 64 + lane;
      if (s < NSLOT) {
        const int g = c0 + 4 * s;
        float4 v;
        v.x = ((unsigned)(g + 0) < (unsigned)L_ROW) ? xrow[g + 0] : 0.0f;
        v.y = ((unsigned)(g + 1) < (unsigned)L_ROW) ? xrow[g + 1] : 0.0f;
        v.z = ((unsigned)(g + 2) < (unsigned)L_ROW) ? xrow[g + 2] : 0.0f;
        v.w = ((unsigned)(g + 3) < (unsigned)L_ROW) ? xrow[g + 3] : 0.0f;
        buf[swz(s)] = v;
      }
    }
    WFENCE();
  }

  // own block -> registers (persists across stages)
  float r[E];
#pragma unroll
  for (int j = 0; j < EF4; ++j) {
    float4 v = buf[swz(b4 + j)];
    r[4*j] = v.x; r[4*j+1] = v.y; r[4*j+2] = v.z; r[4*j+3] = v.w;
  }

  if (!edge) {
    // interior: max51 -> min75 (= min25∘min51) -> max25; pads never reached
    stage_big<51, true >(r, buf, lane, 0, false);
    stage_big<75, false>(r, buf, lane, 0, false);
    stage_25 <true >(r, buf, lane, 0, false);
  } else {
    // exact chain with per-stage zero padding (offsets 25/50/62/74)
    stage_big<51, true >(r, buf, lane, c0 + 25, true);
    stage_big<51, false>(r, buf, lane, c0 + 50, true);
    stage_25 <false>(r, buf, lane, c0 + 62, true);
    stage_25 <true >(r, buf, lane, c0 + 74, true);
  }

  // ---- copy-out. Buffer float l holds out[ob + l - 2], claimed l in
  // [2, T_W+2). Interior: dual-slot LDS repack -> 16B-aligned FULL-WIDTH
  // float4 NT stores (64 lanes x 16B contiguous = full lines; no
  // partial-line NT amplification; output stream doesn't evict L3 input).
  if (!edge) {
#pragma unroll
    for (int it = 0; it < 8; ++it) {
      const int u = it * 64 + lane;
      if (u < T_W / 4) {                    // 486; reads slot u+1 <= 486
        float4 a = buf[swz(u)];
        float4 b = buf[swz(u + 1)];
        f32x4 v = {a.z, a.w, b.x, b.y};     // locals 4u+2 .. 4u+5
        __builtin_nontemporal_store(
            v, reinterpret_cast<f32x4*>(orow + ob + 4 * u));
      }
    }
  } else {
    const int hi = min(ob + T_W, L_ROW);
#pragma unroll
    for (int it = 0; it < 8; ++it) {
      const int u = it * 64 + lane;
      if (u <= T_W / 4) {
        float4 v = buf[swz(u)];
        const int p = ob - 2 + 4 * u;
        if (p     >= ob && p     < hi) orow[p]     = v.x;
        if (p + 1 >= ob && p + 1 < hi) orow[p + 1] = v.y;
        if (p + 2 >= ob && p + 2 < hi) orow[p + 2] = v.z;
        if (p + 3 >= ob && p + 3 < hi) orow[p + 3] = v.w;
      }
    }
  }
}

extern "C" void kernel_launch(void* const* d_in, const int* in_sizes, int n_in,
                              void* d_out, int out_size, void* d_ws, size_t ws_size,
                              hipStream_t stream) {
  const float* x = (const float*)d_in[0];
  float* out = (float*)d_out;
  dim3 grid((N_CHUNKS + 3) / 4, N_ROWS);    // 34 x 128 blocks, 4 waves each
  morph_co_kernel<<<grid, BLOCK, 0, stream>>>(x, out);
}